// Round 3
// baseline (140.073 us; speedup 1.0000x reference)
//
#include <hip/hip_runtime.h>
#include <hip/hip_bf16.h>

// FourierKANLayer: out[n,o] = bias[o] + sum_{i,b} coeffs[o,i,b] * basis[n,i,b]
// basis = [1, sin(m*pi*x) m=1..32, cos(m*pi*x) m=1..32] per (n,i).
//
// R2 design: 32x32x16 bf16 MFMA, 64 rows/wave (two 32-row tiles -> each B-frag
// ds_read feeds 2 MFMAs, halving LDS traffic per FLOP), rotation-form sin/cos
// recurrence (4 arrays of 64 = 256 VGPR state), 1 block/CU (grid 256,
// launch_bounds(256,1)), double-buffered global_load_lds staging.
// Repack: coalesced-read / scattered-2B-write, bias fold via atomicAdd.

typedef __bf16 bf16x8 __attribute__((ext_vector_type(8)));
typedef float  f32x4  __attribute__((ext_vector_type(4)));
typedef float  f32x16 __attribute__((ext_vector_type(16)));

#define PI_F 3.14159265358979323846f

// ---------------------------------------------------------------------------
// Repack coeffs [64][64][65] fp32 -> Bp bf16 in 32x32x16 B-fragment order.
// One thread per input element (coalesced read, scattered 2B write):
//   b==0 -> atomicAdd into bias2sum[o] (bias2sum pre-zeroed via memset)
//   else  frag=(m*8+kc)*2+cc, lane=kq*32+(o&31), t=2*(i&3)+sc
//         Bp[frag*512 + lane*8 + t] = bf16(v)
// ---------------------------------------------------------------------------
__global__ __launch_bounds__(256) void fkan_repack(
    const float* __restrict__ coeffs, __bf16* __restrict__ Bp,
    float* __restrict__ bias2sum) {
  int gid = blockIdx.x * 256 + threadIdx.x;   // 0 .. 266239
  if (gid >= 64 * 64 * 65) return;
  float v = coeffs[gid];
  int b  = gid % 65;                          // magic-mul div by compiler
  int oi = gid / 65;
  int i = oi & 63;
  int o = oi >> 6;
  if (b == 0) {
    atomicAdd(&bias2sum[o], v);
    return;
  }
  int m  = (b - 1) & 31;                      // b in 1..32 -> m=b-1; 33..64 -> b-33
  int sc = (b >= 33) ? 1 : 0;
  int kc = i >> 3;
  int kq = (i >> 2) & 1;
  int cc = o >> 5;
  int frag = (m * 8 + kc) * 2 + cc;
  int lane = kq * 32 + (o & 31);
  int t = 2 * (i & 3) + sc;
  Bp[frag * 512 + lane * 8 + t] = (__bf16)v;
}

// ---------------------------------------------------------------------------
// Stage one mode's 16 KB B-slice: 256 threads x 16 B x 4 rounds, per-wave 4KB.
// ---------------------------------------------------------------------------
__device__ __forceinline__ void stage_slice(const __bf16* __restrict__ Bp,
                                            __bf16* dst, int m, int wave,
                                            int lane) {
  const char* g = (const char*)Bp + (size_t)m * 16384 + wave * 4096 + lane * 16;
  char* l = (char*)dst + wave * 4096;
  #pragma unroll
  for (int r = 0; r < 4; ++r) {
    __builtin_amdgcn_global_load_lds(
        (const __attribute__((address_space(1))) void*)(g + r * 1024),
        (__attribute__((address_space(3))) void*)(l + r * 1024), 16, 0, 0);
  }
}

// ---------------------------------------------------------------------------
// Main kernel: 256 threads = 4 waves; block = 256 rows; wave = 64 rows
// (two 32-row MFMA tiles). Lane: cl=lane&31 row-in-tile, kq=lane>>5 K-half.
// Lane state: 64 (row,i) rotation instances, p = tile*32 + kc*4 + e,
// where i = kc*8 + kq*4 + e. Per mode: 16 ds_read_b128 B-frags, each feeds
// the 2 row-tiles -> 32 MFMA 32x32x16. MFMA-bound (~1024 cyc/SIMD/mode).
// ---------------------------------------------------------------------------
__global__ __launch_bounds__(256, 1) void fkan_main(
    const float* __restrict__ x, const __bf16* __restrict__ Bp,
    const float* __restrict__ bias, const float* __restrict__ bias2sum,
    float* __restrict__ out) {
  __shared__ __bf16 Bs[2][8192];   // 2 x 16 KB double buffer

  int tid  = threadIdx.x;
  int wave = tid >> 6;
  int lane = tid & 63;
  int kq   = lane >> 5;
  int cl   = lane & 31;
  int rowbase = blockIdx.x * 256 + wave * 64;   // wave's 64 rows

  // --- init: sincos(pi*x) for 64 (row,i) instances; state = mode 1 --------
  float s1[64], c1[64], sm[64], cm[64];
  #pragma unroll
  for (int t = 0; t < 2; ++t) {
    const float* xrow = x + (size_t)(rowbase + t * 32 + cl) * 64 + kq * 4;
    #pragma unroll
    for (int kc = 0; kc < 8; ++kc) {
      f32x4 v = *(const f32x4*)(xrow + kc * 8);
      #pragma unroll
      for (int e = 0; e < 4; ++e) {
        int p = t * 32 + kc * 4 + e;
        float ss, cs;
        __sincosf(PI_F * v[e], &ss, &cs);
        s1[p] = ss; c1[p] = cs;     // rotation step
        sm[p] = ss; cm[p] = cs;     // current state = mode 1
      }
    }
  }

  f32x16 acc[2][2];                 // [tile][col-half]
  #pragma unroll
  for (int t = 0; t < 2; ++t)
    #pragma unroll
    for (int c2 = 0; c2 < 2; ++c2)
      #pragma unroll
      for (int r = 0; r < 16; ++r) acc[t][c2][r] = 0.f;

  stage_slice(Bp, &Bs[0][0], 0, wave, lane);
  __syncthreads();

  for (int m = 0; m < 32; ++m) {
    int buf = m & 1;
    if (m < 31) stage_slice(Bp, &Bs[buf ^ 1][0], m + 1, wave, lane);

    #pragma unroll
    for (int kc = 0; kc < 8; ++kc) {
      bf16x8 af0, af1;
      #pragma unroll
      for (int e = 0; e < 4; ++e) {
        af0[2 * e]     = (__bf16)sm[kc * 4 + e];
        af0[2 * e + 1] = (__bf16)cm[kc * 4 + e];
        af1[2 * e]     = (__bf16)sm[32 + kc * 4 + e];
        af1[2 * e + 1] = (__bf16)cm[32 + kc * 4 + e];
      }
      #pragma unroll
      for (int c2 = 0; c2 < 2; ++c2) {
        bf16x8 bf = *(const bf16x8*)(&Bs[buf][(kc * 2 + c2) * 512 + lane * 8]);
        acc[0][c2] = __builtin_amdgcn_mfma_f32_32x32x16_bf16(af0, bf,
                                                             acc[0][c2], 0, 0, 0);
        acc[1][c2] = __builtin_amdgcn_mfma_f32_32x32x16_bf16(af1, bf,
                                                             acc[1][c2], 0, 0, 0);
      }
    }

    if (m < 31) {
      // rotation advance: (s,c) <- (s*c1 + c*s1, c*c1 - s*s1)
      #pragma unroll
      for (int p = 0; p < 64; ++p) {
        float t0 = sm[p];
        sm[p] = fmaf(t0, c1[p],  cm[p] * s1[p]);
        cm[p] = fmaf(cm[p], c1[p], -t0 * s1[p]);
      }
    }
    __syncthreads();
  }

  // --- epilogue: C/D layout col=lane&31, row=(r&3)+8*(r>>2)+4*kq ----------
  #pragma unroll
  for (int c2 = 0; c2 < 2; ++c2) {
    float bv = bias[c2 * 32 + cl] + bias2sum[c2 * 32 + cl];
    #pragma unroll
    for (int t = 0; t < 2; ++t) {
      float* orow = out + (size_t)(rowbase + t * 32) * 64;
      #pragma unroll
      for (int r = 0; r < 16; ++r) {
        int ro = (r & 3) + 8 * (r >> 2) + 4 * kq;
        orow[(size_t)ro * 64 + c2 * 32 + cl] = acc[t][c2][r] + bv;
      }
    }
  }
}

extern "C" void kernel_launch(void* const* d_in, const int* in_sizes, int n_in,
                              void* d_out, int out_size, void* d_ws, size_t ws_size,
                              hipStream_t stream) {
  const float* x      = (const float*)d_in[0];   // [65536, 64]
  const float* coeffs = (const float*)d_in[1];   // [64, 64, 65]
  const float* bias   = (const float*)d_in[2];   // [64]
  float* out = (float*)d_out;

  __bf16* Bp      = (__bf16*)d_ws;               // 512 KB
  float* bias2sum = (float*)((char*)d_ws + 512 * 1024);

  int n_rows = in_sizes[0] / 64;                 // 65536

  hipMemsetAsync(bias2sum, 0, 64 * sizeof(float), stream);
  fkan_repack<<<(64 * 64 * 65 + 255) / 256, 256, 0, stream>>>(coeffs, Bp,
                                                              bias2sum);
  fkan_main<<<n_rows / 256, 256, 0, stream>>>(x, Bp, bias, bias2sum, out);
}